// Round 7
// baseline (593.255 us; speedup 1.0000x reference)
//
#include <hip/hip_runtime.h>

static constexpr int T_LEN = 1024;

typedef _Float16 f16;
typedef f16  f16x4 __attribute__((ext_vector_type(4)));
typedef float f32x4 __attribute__((ext_vector_type(4)));

__device__ __forceinline__ f32x4 mfma16(f16x4 a, f16x4 b, f32x4 c) {
    return __builtin_amdgcn_mfma_f32_16x16x16f16(a, b, c, 0, 0, 0);
}
// 1/(1+2^t): overflow-safe (t->+inf: exp2=inf, rcp->0; t->-inf: ->1)
__device__ __forceinline__ float sig2(float t) {
    return __builtin_amdgcn_rcpf(1.f + __builtin_amdgcn_exp2f(t));
}

// One wave per block, 16 sequences per wave, 256 blocks = 1 wave/CU.
// Fragments (v_mfma_f32_16x16x16f16):
//   A[m][k]: lane = m + 16*(k/4), reg = k%4   (weights, f16, pre-scaled)
//   B[k][n]: lane = n + 16*(k/4), reg = k%4   (H^T: k=hidden, n=seq)
//   D[m][n]: lane = n + 16*(m/4), reg = m%4   (gates: m=row, n=seq)
// B and D share the lane mapping, so updated h feeds the next MFMA directly.
//
// ILP restructure (round-7): layer 2 runs ONE STEP DELAYED. Iteration t
// computes layer-1 step t and layer-2 step t-1; both need only h1[t-1] and
// h2[t-2], so all 8 MFMAs + both activation blocks are independent and
// interleave. pre2[g] = Whh1·h2 + b is computed at the end of each h2
// update (cross-iteration software pipeline), removing the 2-deep MFMA
// chain from the step's critical path.
__global__ void __launch_bounds__(64, 1) lstm2_mfma2_kernel(
    const float* __restrict__ x,
    const float* __restrict__ Wih0, const float* __restrict__ Whh0,
    const float* __restrict__ bih0, const float* __restrict__ bhh0,
    const float* __restrict__ Wih1, const float* __restrict__ Whh1,
    const float* __restrict__ bih1, const float* __restrict__ bhh1,
    const float* __restrict__ Wout, const float* __restrict__ bout,
    float* __restrict__ out)
{
    const int l   = threadIdx.x & 63;
    const int col = l & 15;            // seq within tile (B/C/D col); A row
    const int q   = l >> 4;            // quad index
    const int seq = blockIdx.x * 16 + col;

    const float L2E = 1.442695041f;
    const float NT  = -2.f * L2E;      // tanh(c) scale

    // ---- constant fragments (weights f16, pre-scaled by the gate's -log2e;
    //      tanh group g==2 scaled by -2log2e since tanh(v)=2*sig(2v)-1).
    f16x4 Wa0[4], Wax[4], Wa1[4];      // A-frags: Whh0, Wih1, Whh1
    f32x4 cb1[4], wx0[4], cb2[4];      // D-layout consts: bias1, Wih0, bias2
#pragma unroll
    for (int g = 0; g < 4; ++g) {
        const float ns   = (g == 2) ? (-2.f * L2E) : (-L2E);
        const int   arow = g * 16 + col;       // A: row = lane&15
#pragma unroll
        for (int r = 0; r < 4; ++r) {
            Wa0[g][r] = (f16)(ns * Whh0[arow * 16 + q * 4 + r]);
            Wax[g][r] = (f16)(ns * Wih1[arow * 16 + q * 4 + r]);
            Wa1[g][r] = (f16)(ns * Whh1[arow * 16 + q * 4 + r]);
            const int drow = g * 16 + q * 4 + r;  // D: row = 4q+r
            cb1[g][r] = ns * (bih0[drow] + bhh0[drow]);
            wx0[g][r] = ns * Wih0[drow];
            cb2[g][r] = ns * (bih1[drow] + bhh1[drow]);
        }
    }
#pragma unroll
    for (int g = 0; g < 4; ++g)
        asm volatile("" : "+v"(Wa0[g]), "+v"(Wax[g]), "+v"(Wa1[g]),
                          "+v"(cb1[g]), "+v"(wx0[g]), "+v"(cb2[g]));

    f16x4 h1f = {}, h2f = {};          // h1[t-1], h2[t-2] fragments (f16)
    f32x4 c1 = {0.f, 0.f, 0.f, 0.f}, c2 = {0.f, 0.f, 0.f, 0.f};
    f32x4 h2v = {0.f, 0.f, 0.f, 0.f};
    f32x4 pre2[4];                     // Whh1·h2[t-2] + b2  (pipelined)
#pragma unroll
    for (int g = 0; g < 4; ++g) pre2[g] = cb2[g];

    const float* xb = x + (size_t)seq * T_LEN;
    float4 xq = *reinterpret_cast<const float4*>(xb);

    for (int tb = 0; tb < T_LEN; tb += 4) {
        float4 xn = xq;
        if (tb + 4 < T_LEN)
            xn = *reinterpret_cast<const float4*>(xb + tb + 4);
#pragma unroll
        for (int u = 0; u < 4; ++u) {
            const int   t  = tb + u;
            const float xv = (u==0)?xq.x:(u==1)?xq.y:(u==2)?xq.z:xq.w;

            // ---- issue all 8 independent MFMAs up front:
            //      layer-1 step t and layer-2 step t-1 (both read h1f=h1[t-1])
            f32x4 ga[4], gb[4];
#pragma unroll
            for (int g = 0; g < 4; ++g) {
                f32x4 ci;
#pragma unroll
                for (int r = 0; r < 4; ++r)
                    ci[r] = fmaf(wx0[g][r], xv, cb1[g][r]);
                ga[g] = mfma16(Wa0[g], h1f, ci);
            }
#pragma unroll
            for (int g = 0; g < 4; ++g)
                gb[g] = mfma16(Wax[g], h1f, pre2[g]);

            // ---- layer-2 step t-1: activations + update (uniform guard;
            //      compile-time true for u>=1). Done first so pre2's MFMAs
            //      issue early and overlap layer-1's activation work.
            if (t >= 1) {
                f32x4 sb[4];
#pragma unroll
                for (int g = 0; g < 4; ++g)
#pragma unroll
                    for (int r = 0; r < 4; ++r)
                        sb[g][r] = sig2(gb[g][r]);
#pragma unroll
                for (int r = 0; r < 4; ++r) {
                    const float gg = fmaf(2.f, sb[2][r], -1.f);
                    c2[r] = fmaf(sb[1][r], c2[r], sb[0][r] * gg);
                    const float th = fmaf(2.f, sig2(NT * c2[r]), -1.f);
                    h2v[r] = sb[3][r] * th;
                    h2f[r] = (f16)h2v[r];
                }
#pragma unroll
                for (int g = 0; g < 4; ++g)
                    pre2[g] = mfma16(Wa1[g], h2f, cb2[g]);
            }

            // ---- layer-1 step t: activations + update
            {
                f32x4 sa[4];
#pragma unroll
                for (int g = 0; g < 4; ++g)
#pragma unroll
                    for (int r = 0; r < 4; ++r)
                        sa[g][r] = sig2(ga[g][r]);
#pragma unroll
                for (int r = 0; r < 4; ++r) {
                    const float gg = fmaf(2.f, sa[2][r], -1.f);
                    c1[r] = fmaf(sa[1][r], c1[r], sa[0][r] * gg);
                    const float th = fmaf(2.f, sig2(NT * c1[r]), -1.f);
                    h1f[r] = (f16)(sa[3][r] * th);
                }
            }
        }
        xq = xn;
    }

    // ---- epilogue: layer-2 step T-1 (h1f = h1[T-1], pre2 = Whh1·h2[T-2]+b)
    {
        f32x4 gb[4], sb[4];
#pragma unroll
        for (int g = 0; g < 4; ++g)
            gb[g] = mfma16(Wax[g], h1f, pre2[g]);
#pragma unroll
        for (int g = 0; g < 4; ++g)
#pragma unroll
            for (int r = 0; r < 4; ++r)
                sb[g][r] = sig2(gb[g][r]);
#pragma unroll
        for (int r = 0; r < 4; ++r) {
            const float gg = fmaf(2.f, sb[2][r], -1.f);
            c2[r] = fmaf(sb[1][r], c2[r], sb[0][r] * gg);
            const float th = fmaf(2.f, sig2(NT * c2[r]), -1.f);
            h2v[r] = sb[3][r] * th;
        }
    }

    // ---- head: out[seq][m] = relu(h2) . Wout[m] + bout[m]
    // lane holds h2[u=4q+r][seq=col]; reduce over q via xor-shuffles.
#pragma unroll
    for (int m = 0; m < 5; ++m) {
        float p = 0.f;
#pragma unroll
        for (int r = 0; r < 4; ++r)
            p = fmaf(fmaxf(h2v[r], 0.f), Wout[m * 16 + q * 4 + r], p);
        p += __shfl_xor(p, 16, 64);
        p += __shfl_xor(p, 32, 64);
        if (q == 0) out[seq * 5 + m] = p + bout[m];
    }
}

extern "C" void kernel_launch(void* const* d_in, const int* in_sizes, int n_in,
                              void* d_out, int out_size, void* d_ws, size_t ws_size,
                              hipStream_t stream) {
    const float* x    = (const float*)d_in[0];
    const float* Wih0 = (const float*)d_in[1];
    const float* Whh0 = (const float*)d_in[2];
    const float* bih0 = (const float*)d_in[3];
    const float* bhh0 = (const float*)d_in[4];
    const float* Wih1 = (const float*)d_in[5];
    const float* Whh1 = (const float*)d_in[6];
    const float* bih1 = (const float*)d_in[7];
    const float* bhh1 = (const float*)d_in[8];
    const float* Wout = (const float*)d_in[9];
    const float* bout = (const float*)d_in[10];
    float* out = (float*)d_out;

    const int B = in_sizes[0] / T_LEN;          // 4096
    dim3 grid(B / 16), block(64);               // 1 wave / 16 seqs per block
    hipLaunchKernelGGL(lstm2_mfma2_kernel, grid, block, 0, stream,
                       x, Wih0, Whh0, bih0, bhh0,
                       Wih1, Whh1, bih1, bhh1, Wout, bout, out);
}

// Round 8
// 458.546 us; speedup vs baseline: 1.2938x; 1.2938x over previous
//
#include <hip/hip_runtime.h>

static constexpr int T_LEN = 1024;

typedef _Float16 f16;
typedef f16  f16x4 __attribute__((ext_vector_type(4)));
typedef float f32x4 __attribute__((ext_vector_type(4)));

__device__ __forceinline__ f32x4 mfma16(f16x4 a, f16x4 b, f32x4 c) {
    return __builtin_amdgcn_mfma_f32_16x16x16f16(a, b, c, 0, 0, 0);
}
// 1/(1+2^t): overflow-safe (t->+inf: exp2=inf, rcp->0; t->-inf: ->1)
__device__ __forceinline__ float sig2(float t) {
    return __builtin_amdgcn_rcpf(1.f + __builtin_amdgcn_exp2f(t));
}

// 4 waves per block, 16 sequences per block, 256 blocks = 4 waves/CU
// (one per SIMD). Wave w owns gate group w (PyTorch i,f,g,o) for BOTH
// layers: per-wave transcendental work drops 40->16 sig2 per step, and the
// 4 SIMDs share it. Gate tiles are exchanged via double-buffered LDS with
// ONE barrier per step (slot t&1; reuse at t+2 is ordered through the t+1
// barrier by program order).
// Fragments (v_mfma_f32_16x16x16f16):
//   A[m][k]: lane = m + 16*(k/4), reg = k%4   (weights, f16, pre-scaled)
//   B[k][n]: lane = n + 16*(k/4), reg = k%4   (H^T: k=hidden, n=seq)
//   D[m][n]: lane = n + 16*(m/4), reg = m%4   (gates)
// D and B share the lane mapping, so every wave's redundantly-updated h
// feeds the next step's MFMA directly.
// Layer 2 runs ONE STEP DELAYED (round-7 pipeline): iteration t computes
// L1 step t and L2 step t-1 from h1[t-1], h2[t-2]; pre2 = Whh1·h2 + b2 is
// refreshed right after each h2 update.
__global__ void __launch_bounds__(256, 1) lstm2_gs_kernel(
    const float* __restrict__ x,
    const float* __restrict__ Wih0, const float* __restrict__ Whh0,
    const float* __restrict__ bih0, const float* __restrict__ bhh0,
    const float* __restrict__ Wih1, const float* __restrict__ Whh1,
    const float* __restrict__ bih1, const float* __restrict__ bhh1,
    const float* __restrict__ Wout, const float* __restrict__ bout,
    float* __restrict__ out)
{
    const int tid = threadIdx.x;
    const int w   = tid >> 6;          // gate group owned by this wave
    const int l   = tid & 63;
    const int col = l & 15;            // seq within tile; A within-block row
    const int q   = l >> 4;
    const int seq = blockIdx.x * 16 + col;

    // [slot][layer][gate][lane*4]: 16 KB, per-lane 16B contiguous.
    __shared__ __align__(16) float smem[2][2][4][256];

    const float L2E = 1.442695041f;
    const float NT  = -2.f * L2E;      // tanh(c) scale
    const float ns  = (w == 2) ? (-2.f * L2E) : (-L2E);  // gate pre-scale

    // ---- this wave's constant fragments (f16 weights, pre-scaled).
    f16x4 Wa0, Wax, Wa1;               // A-frags: Whh0, Wih1, Whh1 (group w)
    f32x4 cb1, wx0, cb2;               // D-layout consts: bias1, Wih0, bias2
    {
        const int arow = w * 16 + col;
#pragma unroll
        for (int r = 0; r < 4; ++r) {
            Wa0[r] = (f16)(ns * Whh0[arow * 16 + q * 4 + r]);
            Wax[r] = (f16)(ns * Wih1[arow * 16 + q * 4 + r]);
            Wa1[r] = (f16)(ns * Whh1[arow * 16 + q * 4 + r]);
            const int drow = w * 16 + q * 4 + r;
            cb1[r] = ns * (bih0[drow] + bhh0[drow]);
            wx0[r] = ns * Wih0[drow];
            cb2[r] = ns * (bih1[drow] + bhh1[drow]);
        }
    }
    asm volatile("" : "+v"(Wa0), "+v"(Wax), "+v"(Wa1),
                      "+v"(cb1), "+v"(wx0), "+v"(cb2));

    f16x4 h1f = {}, h2f = {};          // h1[t-1], h2[t-2] (B layout, f16)
    f32x4 c1 = {0.f, 0.f, 0.f, 0.f}, c2 = {0.f, 0.f, 0.f, 0.f};
    f32x4 h2v = {0.f, 0.f, 0.f, 0.f};
    f32x4 pre2 = cb2;                  // Whh1·h2[t-2] + b2 (h2[-1]=0)

    const float* xb = x + (size_t)seq * T_LEN;
    float4 xq = *reinterpret_cast<const float4*>(xb);

    for (int tb = 0; tb < T_LEN; tb += 4) {
        float4 xn = xq;
        if (tb + 4 < T_LEN)
            xn = *reinterpret_cast<const float4*>(xb + tb + 4);
#pragma unroll
        for (int u = 0; u < 4; ++u) {
            const int   t    = tb + u;
            const int   slot = u & 1;          // == t&1
            const float xv   = (u==0)?xq.x:(u==1)?xq.y:(u==2)?xq.z:xq.w;

            // ---- phase A: this wave's gate tile for L1 step t and L2
            //      step t-1, sigmoid'd (tanh group fixed up), into LDS.
            f32x4 ci;
#pragma unroll
            for (int r = 0; r < 4; ++r)
                ci[r] = fmaf(wx0[r], xv, cb1[r]);
            const f32x4 ga = mfma16(Wa0, h1f, ci);
            const f32x4 gb = mfma16(Wax, h1f, pre2);
            f32x4 sa, sb;
#pragma unroll
            for (int r = 0; r < 4; ++r) { sa[r] = sig2(ga[r]); sb[r] = sig2(gb[r]); }
            if (w == 2) {
#pragma unroll
                for (int r = 0; r < 4; ++r) {
                    sa[r] = fmaf(2.f, sa[r], -1.f);
                    sb[r] = fmaf(2.f, sb[r], -1.f);
                }
            }
            *reinterpret_cast<f32x4*>(&smem[slot][0][w][l * 4]) = sa;
            *reinterpret_cast<f32x4*>(&smem[slot][1][w][l * 4]) = sb;
            __syncthreads();

            // ---- phase B: gather all gates; redundant elementwise update.
            const f32x4 A0 = *reinterpret_cast<const f32x4*>(&smem[slot][0][0][l * 4]);
            const f32x4 A1 = *reinterpret_cast<const f32x4*>(&smem[slot][0][1][l * 4]);
            const f32x4 A2 = *reinterpret_cast<const f32x4*>(&smem[slot][0][2][l * 4]);
            const f32x4 A3 = *reinterpret_cast<const f32x4*>(&smem[slot][0][3][l * 4]);
            const f32x4 B0 = *reinterpret_cast<const f32x4*>(&smem[slot][1][0][l * 4]);
            const f32x4 B1 = *reinterpret_cast<const f32x4*>(&smem[slot][1][1][l * 4]);
            const f32x4 B2 = *reinterpret_cast<const f32x4*>(&smem[slot][1][2][l * 4]);
            const f32x4 B3 = *reinterpret_cast<const f32x4*>(&smem[slot][1][3][l * 4]);

            if (t >= 1) {                       // L2 step t-1
#pragma unroll
                for (int r = 0; r < 4; ++r) {
                    c2[r] = fmaf(B1[r], c2[r], B0[r] * B2[r]);
                    const float th = fmaf(2.f, sig2(NT * c2[r]), -1.f);
                    h2v[r] = B3[r] * th;
                    h2f[r] = (f16)h2v[r];
                }
                pre2 = mfma16(Wa1, h2f, cb2);
            }
#pragma unroll
            for (int r = 0; r < 4; ++r) {       // L1 step t
                c1[r] = fmaf(A1[r], c1[r], A0[r] * A2[r]);
                const float th = fmaf(2.f, sig2(NT * c1[r]), -1.f);
                h1f[r] = (f16)(A3[r] * th);
            }
        }
        xq = xn;
    }

    // ---- epilogue: L2 step T-1 (h1f = h1[T-1], pre2 = Whh1·h2[T-2]+b2)
    {
        const f32x4 gb = mfma16(Wax, h1f, pre2);
        f32x4 sb;
#pragma unroll
        for (int r = 0; r < 4; ++r) sb[r] = sig2(gb[r]);
        if (w == 2) {
#pragma unroll
            for (int r = 0; r < 4; ++r) sb[r] = fmaf(2.f, sb[r], -1.f);
        }
        *reinterpret_cast<f32x4*>(&smem[0][1][w][l * 4]) = sb;
        __syncthreads();
        const f32x4 B0 = *reinterpret_cast<const f32x4*>(&smem[0][1][0][l * 4]);
        const f32x4 B1 = *reinterpret_cast<const f32x4*>(&smem[0][1][1][l * 4]);
        const f32x4 B2 = *reinterpret_cast<const f32x4*>(&smem[0][1][2][l * 4]);
        const f32x4 B3 = *reinterpret_cast<const f32x4*>(&smem[0][1][3][l * 4]);
#pragma unroll
        for (int r = 0; r < 4; ++r) {
            c2[r] = fmaf(B1[r], c2[r], B0[r] * B2[r]);
            const float th = fmaf(2.f, sig2(NT * c2[r]), -1.f);
            h2v[r] = B3[r] * th;
        }
    }

    // ---- head (wave 0 only): out[seq][m] = relu(h2) . Wout[m] + bout[m]
    if (w == 0) {
#pragma unroll
        for (int m = 0; m < 5; ++m) {
            float p = 0.f;
#pragma unroll
            for (int r = 0; r < 4; ++r)
                p = fmaf(fmaxf(h2v[r], 0.f), Wout[m * 16 + q * 4 + r], p);
            p += __shfl_xor(p, 16, 64);
            p += __shfl_xor(p, 32, 64);
            if (q == 0) out[seq * 5 + m] = p + bout[m];
        }
    }
}

extern "C" void kernel_launch(void* const* d_in, const int* in_sizes, int n_in,
                              void* d_out, int out_size, void* d_ws, size_t ws_size,
                              hipStream_t stream) {
    const float* x    = (const float*)d_in[0];
    const float* Wih0 = (const float*)d_in[1];
    const float* Whh0 = (const float*)d_in[2];
    const float* bih0 = (const float*)d_in[3];
    const float* bhh0 = (const float*)d_in[4];
    const float* Wih1 = (const float*)d_in[5];
    const float* Whh1 = (const float*)d_in[6];
    const float* bih1 = (const float*)d_in[7];
    const float* bhh1 = (const float*)d_in[8];
    const float* Wout = (const float*)d_in[9];
    const float* bout = (const float*)d_in[10];
    float* out = (float*)d_out;

    const int B = in_sizes[0] / T_LEN;          // 4096
    dim3 grid(B / 16), block(256);              // 4 waves / 16 seqs per block
    hipLaunchKernelGGL(lstm2_gs_kernel, grid, block, 0, stream,
                       x, Wih0, Whh0, bih0, bhh0,
                       Wih1, Whh1, bih1, bhh1, Wout, bout, out);
}